// Round 3
// baseline (150.369 us; speedup 1.0000x reference)
//
#include <hip/hip_runtime.h>
#include <hip/hip_bf16.h>
#include <math.h>

#define T 4000
#define C 128
#define NB 800                 // T/5
#define KTILES 250             // T/16
#define NBLOCKS 50             // T/80
#define CFRAC (1598.0f/3995.0f)

typedef short bf16x8 __attribute__((ext_vector_type(8)));
typedef float f32x4 __attribute__((ext_vector_type(4)));

// ---------------- Kernel 1: normalize rows -> bf16; reset arrival counter ----------------
__global__ __launch_bounds__(256) void norm_kernel(const float* __restrict__ x,
                                                   __hip_bfloat16* __restrict__ xnb,
                                                   unsigned* __restrict__ counter) {
    if (blockIdx.x == 0 && threadIdx.x == 0) *counter = 0u;
    const int row = blockIdx.x * 4 + (threadIdx.x >> 6);   // grid 1000 x 256 = 4000 rows
    const int lane = threadIdx.x & 63;
    const float* xr = x + (size_t)row * C;
    float a = xr[lane], b = xr[lane + 64];
    float ss = a * a + b * b;
    for (int off = 32; off; off >>= 1) ss += __shfl_xor(ss, off);
    float inv = 1.0f / fmaxf(sqrtf(ss), 1e-8f);
    __hip_bfloat16* orow = xnb + (size_t)row * C;
    orow[lane]      = __float2bfloat16(a * inv);
    orow[lane + 64] = __float2bfloat16(b * inv);
}

// ---------------- Kernel 2: fused rowsum (MFMA) + per-5-block loss + finalize ----------------
// Block = 80 i-rows = 5 row-groups x 16 rows; 10 waves = (rowgroup g = w>>1, k-parity = w&1).
// Wave holds its 16-row A frags in regs, sweeps k-tiles of 16 cols (stride 2), B frags
// straight from global (L2-resident). Captures in-5-block sims to LDS, accumulates
// exp-rowsums in regs. Then the block computes its 16 five-blocks' loss terms.
// Last-arriving block reduces the 50 partials and writes out (no memsets anywhere).
__global__ __launch_bounds__(640) void main_kernel(const __hip_bfloat16* __restrict__ xnb,
                                                   const int* __restrict__ kuai2p,
                                                   float* __restrict__ partials,
                                                   unsigned* __restrict__ counter,
                                                   float* __restrict__ out) {
    __shared__ float s5[80][5];     // raw in-5-block sims (cols local 0..4)
    __shared__ float rsp[2][80];    // per-k-parity partial rowsums
    __shared__ float wsum[10];
    __shared__ bool amLast;

    const int bid  = blockIdx.x;     // 0..49
    const int tid  = threadIdx.x;
    const int w    = tid >> 6;       // 0..9
    const int lane = tid & 63;
    const int g    = w >> 1;         // rowgroup 0..4
    const int kpar = w & 1;
    const int r    = lane & 15;
    const int hi   = lane >> 4;      // 0..3
    const int ko   = hi * 8;
    const int i0   = bid * 80 + g * 16;

    bf16x8 afrag[4];
    const __hip_bfloat16* arow = xnb + (size_t)(i0 + r) * C;
#pragma unroll
    for (int kc = 0; kc < 4; ++kc)
        afrag[kc] = *(const bf16x8*)(arow + kc * 32 + ko);

    f32x4 rsum = {0.f, 0.f, 0.f, 0.f};
    const int kt0 = bid * 5;

#pragma unroll 2
    for (int kt = kpar; kt < KTILES; kt += 2) {
        const __hip_bfloat16* brow = xnb + (size_t)(kt * 16 + r) * C;
        f32x4 acc = {0.f, 0.f, 0.f, 0.f};
#pragma unroll
        for (int kc = 0; kc < 4; ++kc) {
            bf16x8 bfrag = *(const bf16x8*)(brow + kc * 32 + ko);
            acc = __builtin_amdgcn_mfma_f32_16x16x32_bf16(afrag[kc], bfrag, acc, 0, 0, 0);
        }
        if ((unsigned)(kt - kt0) < 5u) {           // wave-uniform: this k-tile overlaps our 80 cols
            int lj  = kt * 16 + r - bid * 80;      // local col 0..79
            int ljb = lj / 5;
#pragma unroll
            for (int j = 0; j < 4; ++j) {
                int li = g * 16 + hi * 4 + j;      // local row of acc[j]
                if (li / 5 == ljb) s5[li][lj - ljb * 5] = acc[j];
            }
        }
#pragma unroll
        for (int j = 0; j < 4; ++j) rsum[j] += __expf(acc[j]);
    }

    // fold the 16 k-columns (low 4 lane bits)
#pragma unroll
    for (int off = 1; off < 16; off <<= 1)
#pragma unroll
        for (int j = 0; j < 4; ++j) rsum[j] += __shfl_xor(rsum[j], off);

    if (r == 0) {
#pragma unroll
        for (int j = 0; j < 4; ++j) rsp[kpar][g * 16 + hi * 4 + j] = rsum[j];
    }
    __syncthreads();

    // ---- loss phase: 16 five-blocks x 20 ordered pairs = 320 terms ----
    float contrib = 0.f;
    if (tid < 320) {
        int fb = tid / 20;
        int p  = tid % 20;
        int pi = p >> 2;
        int rr = p & 3;
        int pj = rr + (rr >= pi ? 1 : 0);
        int li = fb * 5 + pi;
        float sij = s5[li][pj];
        float bsum = 0.f;
#pragma unroll
        for (int m = 0; m < 5; ++m) bsum += __expf(s5[li][m]);
        float rs = rsp[0][li] + rsp[1][li];
        float negE = CFRAC * (rs - bsum);          // E[neg_sum]
        contrib = sij - __logf(negE + __expf(sij)); // log(pos/(neg+pos))
    }
#pragma unroll
    for (int off = 32; off; off >>= 1) contrib += __shfl_xor(contrib, off);
    if (lane == 0) wsum[w] = contrib;
    __syncthreads();

    if (tid == 0) {
        float s = 0.f;
#pragma unroll
        for (int i = 0; i < 10; ++i) s += wsum[i];
        partials[bid] = s;
        __threadfence();                            // device-scope release
        unsigned prev = atomicAdd(counter, 1u);
        amLast = (prev == NBLOCKS - 1);
    }
    __syncthreads();

    if (amLast && w == 0) {
        __threadfence();                            // acquire
        float s = (lane < NBLOCKS) ? partials[lane] : 0.f;
#pragma unroll
        for (int off = 32; off; off >>= 1) s += __shfl_xor(s, off);
        if (lane == 0) {
            int k = *kuai2p;
            out[0] = -s / ((float)NB * (float)k * (float)(k - 1));
        }
    }
}

extern "C" void kernel_launch(void* const* d_in, const int* in_sizes, int n_in,
                              void* d_out, int out_size, void* d_ws, size_t ws_size,
                              hipStream_t stream) {
    const float* x = (const float*)d_in[0];
    const int* kuai2 = (const int*)d_in[1];
    float* out = (float*)d_out;

    float* partials = (float*)d_ws;                       // 64 floats
    unsigned* counter = (unsigned*)(partials + 64);       // 1 u32 (+pad)
    __hip_bfloat16* xnb = (__hip_bfloat16*)(partials + 128); // T*C bf16

    norm_kernel<<<T / 4, 256, 0, stream>>>(x, xnb, counter);
    main_kernel<<<NBLOCKS, 640, 0, stream>>>(xnb, kuai2, partials, counter, out);
}

// Round 4
// 123.847 us; speedup vs baseline: 1.2142x; 1.2142x over previous
//
#include <hip/hip_runtime.h>
#include <hip/hip_bf16.h>
#include <math.h>

#define T 4000
#define C 128
#define NB 800                 // T/5
#define KTILES 250             // T/16
#define NSTRIPE 50             // T/80
#define KSPLIT 20              // k-slices per stripe
#define CFRAC (1598.0f/3995.0f)

typedef short bf16x8 __attribute__((ext_vector_type(8)));
typedef float f32x4 __attribute__((ext_vector_type(4)));

// ws layout (floats):
//   [0]        lossAcc
//   [1]        counter2 (u32)
//   [2..51]    stripe counters (u32)
//   [64..4063] rowsum[T]
//   [8192...]  xnb bf16 [T*C]

__device__ inline float bf2f(short s) {
    union { unsigned u; float f; } v;
    v.u = ((unsigned)(unsigned short)s) << 16;
    return v.f;
}

// fp32 dot of two bf16 rows (vectorized loads)
__device__ inline float bdot(const __hip_bfloat16* a, const __hip_bfloat16* b) {
    float d = 0.f;
#pragma unroll
    for (int c = 0; c < C; c += 8) {
        bf16x8 va = *(const bf16x8*)(a + c);
        bf16x8 vb = *(const bf16x8*)(b + c);
#pragma unroll
        for (int e = 0; e < 8; ++e) d += bf2f(va[e]) * bf2f(vb[e]);
    }
    return d;
}

// ---------------- Kernel 1: normalize -> bf16; zero rowsum + controls ----------------
__global__ __launch_bounds__(256) void norm_kernel(const float* __restrict__ x,
                                                   __hip_bfloat16* __restrict__ xnb,
                                                   float* __restrict__ rowsum,
                                                   unsigned* __restrict__ ctrl) {
    const int tid = threadIdx.x;
    if (blockIdx.x == 0 && tid < 64) ctrl[tid] = 0u;   // lossAcc, counter2, stripe counters
    const int row = blockIdx.x * 4 + (tid >> 6);        // grid 1000 -> 4000 rows
    const int lane = tid & 63;
    if (lane == 0) rowsum[row] = 0.f;
    const float* xr = x + (size_t)row * C;
    float a = xr[lane], b = xr[lane + 64];
    float ss = a * a + b * b;
    for (int off = 32; off; off >>= 1) ss += __shfl_xor(ss, off);
    float inv = 1.0f / fmaxf(sqrtf(ss), 1e-8f);
    __hip_bfloat16* orow = xnb + (size_t)row * C;
    orow[lane]      = __float2bfloat16(a * inv);
    orow[lane + 64] = __float2bfloat16(b * inv);
}

// ---------------- Kernel 2: rowsum MFMA + per-stripe loss tail + finalize ----------------
// grid (NSTRIPE, KSPLIT), 320 threads = 5 waves; wave w owns rows [bi*80+w*16, +16).
// Wave holds A frags in regs, sweeps k-tiles kt = ks, ks+20, ... (12-13 iters),
// B frags direct from global (L2/L1-resident), atomicAdd into rowsum.
// Last-arriving block of each stripe computes the stripe's 16 five-blocks' loss;
// last of the 50 stripe-finishers writes out.
__global__ __launch_bounds__(320) void main_kernel(const __hip_bfloat16* __restrict__ xnb,
                                                   const int* __restrict__ kuai2p,
                                                   float* __restrict__ rowsum,
                                                   float* __restrict__ lossAcc,
                                                   unsigned* __restrict__ ctrl,
                                                   float* __restrict__ out) {
    __shared__ float s5[16][5][5];
    __shared__ float wpart[5];
    __shared__ bool amLast;

    unsigned* counter2 = ctrl + 1;
    unsigned* scnt     = ctrl + 2;

    const int bi   = blockIdx.x;      // stripe 0..49
    const int ks   = blockIdx.y;      // k-slice 0..19
    const int tid  = threadIdx.x;
    const int w    = tid >> 6;        // row-group 0..4
    const int lane = tid & 63;
    const int r    = lane & 15;
    const int hi   = lane >> 4;       // 0..3
    const int ko   = hi * 8;
    const int i0   = bi * 80 + w * 16;

    bf16x8 afrag[4];
    const __hip_bfloat16* arow = xnb + (size_t)(i0 + r) * C;
#pragma unroll
    for (int kc = 0; kc < 4; ++kc)
        afrag[kc] = *(const bf16x8*)(arow + kc * 32 + ko);

    f32x4 rsum = {0.f, 0.f, 0.f, 0.f};
#pragma unroll 2
    for (int kt = ks; kt < KTILES; kt += KSPLIT) {
        const __hip_bfloat16* brow = xnb + (size_t)(kt * 16 + r) * C;
        f32x4 acc = {0.f, 0.f, 0.f, 0.f};
#pragma unroll
        for (int kc = 0; kc < 4; ++kc) {
            bf16x8 bfrag = *(const bf16x8*)(brow + kc * 32 + ko);
            acc = __builtin_amdgcn_mfma_f32_16x16x32_bf16(afrag[kc], bfrag, acc, 0, 0, 0);
        }
#pragma unroll
        for (int j = 0; j < 4; ++j) rsum[j] += __expf(acc[j]);
    }

    // fold the 16 k-columns (low 4 lane bits)
#pragma unroll
    for (int off = 1; off < 16; off <<= 1)
#pragma unroll
        for (int j = 0; j < 4; ++j) rsum[j] += __shfl_xor(rsum[j], off);

    if (r == 0) {
#pragma unroll
        for (int j = 0; j < 4; ++j)
            atomicAdd(&rowsum[i0 + hi * 4 + j], rsum[j]);
    }

    // ---- stripe arrival: release our atomics, bump stripe counter ----
    __threadfence();
    __syncthreads();
    if (tid == 0) {
        unsigned prev = atomicAdd(&scnt[bi], 1u);
        amLast = (prev == KSPLIT - 1);
    }
    __syncthreads();
    if (!amLast) return;
    __threadfence();   // acquire: all 20 slices' rowsum atomics now visible

    // ---- loss tail for this stripe's 16 five-blocks ----
    const int base = bi * 80;
    for (int s = tid; s < 400; s += 320) {
        int fb = s / 25, p = s % 25, pi = p / 5, pj = p % 5;
        s5[fb][pi][pj] = bdot(xnb + (size_t)(base + fb * 5 + pi) * C,
                              xnb + (size_t)(base + fb * 5 + pj) * C);
    }
    __syncthreads();

    float contrib = 0.f;
    {
        int fb = tid / 20, p = tid % 20;
        int pi = p >> 2, rr = p & 3;
        int pj = rr + (rr >= pi ? 1 : 0);
        float sij = s5[fb][pi][pj];
        float bsum = 0.f;
#pragma unroll
        for (int m = 0; m < 5; ++m) bsum += __expf(s5[fb][pi][m]);
        float rs = __hip_atomic_load(&rowsum[base + fb * 5 + pi],
                                     __ATOMIC_RELAXED, __HIP_MEMORY_SCOPE_AGENT);
        float negE = CFRAC * (rs - bsum);            // E[neg_sum]
        contrib = sij - __logf(negE + __expf(sij));  // log(pos/(neg+pos))
    }
#pragma unroll
    for (int off = 32; off; off >>= 1) contrib += __shfl_xor(contrib, off);
    if (lane == 0) wpart[w] = contrib;
    __syncthreads();

    if (tid == 0) {
        float sblk = wpart[0] + wpart[1] + wpart[2] + wpart[3] + wpart[4];
        atomicAdd(lossAcc, sblk);
        __threadfence();
        unsigned prev = atomicAdd(counter2, 1u);
        if (prev == NSTRIPE - 1) {
            __threadfence();
            float tot = __hip_atomic_load(lossAcc, __ATOMIC_RELAXED,
                                          __HIP_MEMORY_SCOPE_AGENT);
            int k = *kuai2p;
            out[0] = -tot / ((float)NB * (float)k * (float)(k - 1));
        }
    }
}

extern "C" void kernel_launch(void* const* d_in, const int* in_sizes, int n_in,
                              void* d_out, int out_size, void* d_ws, size_t ws_size,
                              hipStream_t stream) {
    const float* x = (const float*)d_in[0];
    const int* kuai2 = (const int*)d_in[1];
    float* out = (float*)d_out;

    float* ws = (float*)d_ws;
    float* lossAcc = ws;                       // [0]
    unsigned* ctrl = (unsigned*)ws;            // [0..63] control words ([0] aliases lossAcc: zeroed)
    float* rowsum = ws + 64;                   // [64..4063]
    __hip_bfloat16* xnb = (__hip_bfloat16*)(ws + 8192);

    norm_kernel<<<T / 4, 256, 0, stream>>>(x, xnb, rowsum, ctrl);

    dim3 grid(NSTRIPE, KSPLIT);
    main_kernel<<<grid, 320, 0, stream>>>(xnb, kuai2, rowsum, lossAcc, ctrl, out);
}

// Round 5
// 79.148 us; speedup vs baseline: 1.8999x; 1.5648x over previous
//
#include <hip/hip_runtime.h>
#include <hip/hip_bf16.h>
#include <math.h>

#define T 4000
#define C 128
#define NB 800                 // T/5
#define KTILES 250             // T/16
#define NSTRIPE 50             // T/80 stripes of 80 i-rows
#define KSPLIT 20              // k-slices per stripe
#define CFRAC (1598.0f/3995.0f)

typedef short bf16x8 __attribute__((ext_vector_type(8)));
typedef float f32x4 __attribute__((ext_vector_type(4)));

// float -> bf16 bits, round-to-nearest-even (inputs are normal finite floats)
__device__ inline short f2bf(float f) {
    union { float f; unsigned u; } v; v.f = f;
    unsigned r = v.u + 0x7fffu + ((v.u >> 16) & 1u);
    return (short)(r >> 16);
}

// ---------------- Kernel 1: fused normalize + partial rowsums ----------------
// grid (NSTRIPE, KSPLIT) x 320 threads (5 waves of 16 i-rows each).
// Wave lane (hi=lane>>4, r=lane&15) holds channels {kc*32+hi*8+e} of row (.. + r):
// the 4 hi-groups cover all 128 channels, so per-row sumsq = 2 shfl_xor folds.
// A-frags normalized+converted once; B-tiles streamed from fp32 x (L2-resident),
// normalized on the fly. Partial exp-rowsums plain-stored to rpart[ks][row].
// No atomics, no fences — the kernel boundary is the barrier.
__global__ __launch_bounds__(320) void rowsum_kernel(const float* __restrict__ x,
                                                     float* __restrict__ rpart,
                                                     float* __restrict__ out) {
    const int bi = blockIdx.x;      // stripe 0..49
    const int ks = blockIdx.y;      // k-slice 0..19
    const int tid = threadIdx.x;
    if (bi == 0 && ks == 0 && tid == 0) out[0] = 0.f;   // visible to K2 after boundary
    const int w = tid >> 6, lane = tid & 63;
    const int r = lane & 15, hi = lane >> 4;
    const int i0 = bi * 80 + w * 16;

    // ---- A rows: load fp32, norm on the fly, convert to bf16 frags ----
    const float* arow = x + (size_t)(i0 + r) * C;
    float av[32];
    float ss = 0.f;
#pragma unroll
    for (int kc = 0; kc < 4; ++kc) {
        float4 u = *(const float4*)(arow + kc * 32 + hi * 8);
        float4 v = *(const float4*)(arow + kc * 32 + hi * 8 + 4);
        av[kc*8+0]=u.x; av[kc*8+1]=u.y; av[kc*8+2]=u.z; av[kc*8+3]=u.w;
        av[kc*8+4]=v.x; av[kc*8+5]=v.y; av[kc*8+6]=v.z; av[kc*8+7]=v.w;
        ss += u.x*u.x + u.y*u.y + u.z*u.z + u.w*u.w
            + v.x*v.x + v.y*v.y + v.z*v.z + v.w*v.w;
    }
    ss += __shfl_xor(ss, 16);
    ss += __shfl_xor(ss, 32);
    float inv = 1.0f / fmaxf(sqrtf(ss), 1e-8f);
    bf16x8 afrag[4];
#pragma unroll
    for (int kc = 0; kc < 4; ++kc)
#pragma unroll
        for (int e = 0; e < 8; ++e) afrag[kc][e] = f2bf(av[kc*8+e] * inv);

    // ---- k-sweep ----
    f32x4 rsum = {0.f, 0.f, 0.f, 0.f};
    for (int kt = ks; kt < KTILES; kt += KSPLIT) {
        const float* brow = x + (size_t)(kt * 16 + r) * C;
        float bv[32];
        float ssb = 0.f;
#pragma unroll
        for (int kc = 0; kc < 4; ++kc) {
            float4 u = *(const float4*)(brow + kc * 32 + hi * 8);
            float4 v = *(const float4*)(brow + kc * 32 + hi * 8 + 4);
            bv[kc*8+0]=u.x; bv[kc*8+1]=u.y; bv[kc*8+2]=u.z; bv[kc*8+3]=u.w;
            bv[kc*8+4]=v.x; bv[kc*8+5]=v.y; bv[kc*8+6]=v.z; bv[kc*8+7]=v.w;
            ssb += u.x*u.x + u.y*u.y + u.z*u.z + u.w*u.w
                 + v.x*v.x + v.y*v.y + v.z*v.z + v.w*v.w;
        }
        ssb += __shfl_xor(ssb, 16);
        ssb += __shfl_xor(ssb, 32);
        float invb = 1.0f / fmaxf(sqrtf(ssb), 1e-8f);
        f32x4 acc = {0.f, 0.f, 0.f, 0.f};
#pragma unroll
        for (int kc = 0; kc < 4; ++kc) {
            bf16x8 bfrag;
#pragma unroll
            for (int e = 0; e < 8; ++e) bfrag[e] = f2bf(bv[kc*8+e] * invb);
            acc = __builtin_amdgcn_mfma_f32_16x16x32_bf16(afrag[kc], bfrag, acc, 0, 0, 0);
        }
#pragma unroll
        for (int j = 0; j < 4; ++j) rsum[j] += __expf(acc[j]);
    }

    // fold the 16 k-columns (low 4 lane bits); then r==0 lanes store float4
#pragma unroll
    for (int off = 1; off < 16; off <<= 1)
#pragma unroll
        for (int j = 0; j < 4; ++j) rsum[j] += __shfl_xor(rsum[j], off);

    if (r == 0)
        *(f32x4*)(rpart + (size_t)ks * T + i0 + hi * 4) = rsum;
}

// ---------------- Kernel 2: per-5-block loss (one block per 5-block) ----------------
__global__ __launch_bounds__(64) void loss_kernel(const float* __restrict__ x,
                                                  const float* __restrict__ rpart,
                                                  const int* __restrict__ kuai2p,
                                                  float* __restrict__ out) {
    __shared__ float xs[5][C];
    __shared__ float d[5][5];
    const int b = blockIdx.x;
    const int base = b * 5;
    const int t = threadIdx.x;

    // load 5 raw fp32 rows (160 float4)
    for (int i = t; i < 160; i += 64) {
        int row = i >> 5, c4 = i & 31;
        *(float4*)&xs[row][c4 * 4] = *(const float4*)(x + (size_t)(base + row) * C + c4 * 4);
    }
    __syncthreads();

    if (t < 25) {
        int pi = t / 5, pj = t % 5;
        float s = 0.f;
#pragma unroll
        for (int c = 0; c < C; ++c) s += xs[pi][c] * xs[pj][c];
        d[pi][pj] = s;
    }
    __syncthreads();

    float contrib = 0.f;
    if (t < 20) {
        int pi = t >> 2, rr = t & 3;
        int pj = rr + (rr >= pi ? 1 : 0);
        float sii = d[pi][pi];
        float bsum = 0.f, sij = 0.f;
#pragma unroll
        for (int m = 0; m < 5; ++m) {
            float s = d[pi][m] * rsqrtf(sii * d[m][m]);   // cosine sim, fp32
            bsum += __expf(s);
            if (m == pj) sij = s;
        }
        float rs = 0.f;
#pragma unroll
        for (int k2 = 0; k2 < KSPLIT; ++k2) rs += rpart[(size_t)k2 * T + base + pi];
        float negE = CFRAC * (rs - bsum);                 // E[neg_sum]
        contrib = sij - __logf(negE + __expf(sij));       // log(pos/(neg+pos))
    }
#pragma unroll
    for (int off = 32; off; off >>= 1) contrib += __shfl_xor(contrib, off);

    if (t == 0) {
        int k = *kuai2p;
        atomicAdd(out, contrib * (-1.0f / ((float)NB * (float)k * (float)(k - 1))));
    }
}

extern "C" void kernel_launch(void* const* d_in, const int* in_sizes, int n_in,
                              void* d_out, int out_size, void* d_ws, size_t ws_size,
                              hipStream_t stream) {
    const float* x = (const float*)d_in[0];
    const int* kuai2 = (const int*)d_in[1];
    float* out = (float*)d_out;
    float* rpart = (float*)d_ws;             // KSPLIT * T floats = 320 KB

    dim3 g1(NSTRIPE, KSPLIT);
    rowsum_kernel<<<g1, 320, 0, stream>>>(x, rpart, out);
    loss_kernel<<<NB, 64, 0, stream>>>(x, rpart, kuai2, out);
}

// Round 6
// 59.484 us; speedup vs baseline: 2.5279x; 1.3306x over previous
//
#include <hip/hip_runtime.h>
#include <hip/hip_bf16.h>
#include <math.h>

#define T 4000
#define C 128
#define NB 800                 // T/5
#define KTILES 250             // T/16
#define NSTRIPE 50             // T/80 stripes of 80 i-rows
#define KSPLIT 32              // k-slices (grid.y); 250/32 -> 7-8 k-tiles per block
#define CFRAC (1598.0f/3995.0f)

typedef short bf16x8 __attribute__((ext_vector_type(8)));
typedef float f32x4 __attribute__((ext_vector_type(4)));

// ---------------- Kernel 0: normalize rows -> bf16 xnb; zero out ----------------
__global__ __launch_bounds__(256) void norm_kernel(const float* __restrict__ x,
                                                   __hip_bfloat16* __restrict__ xnb,
                                                   float* __restrict__ out) {
    if (blockIdx.x == 0 && threadIdx.x == 0) out[0] = 0.f;  // visible to K2 after boundary
    const int row = blockIdx.x * 4 + (threadIdx.x >> 6);     // grid 1000 -> 4000 rows
    const int lane = threadIdx.x & 63;
    const float* xr = x + (size_t)row * C;
    float a = xr[lane], b = xr[lane + 64];
    float ss = a * a + b * b;
    for (int off = 32; off; off >>= 1) ss += __shfl_xor(ss, off);
    float inv = 1.0f / fmaxf(sqrtf(ss), 1e-8f);
    __hip_bfloat16* orow = xnb + (size_t)row * C;
    orow[lane]      = __float2bfloat16(a * inv);
    orow[lane + 64] = __float2bfloat16(b * inv);
}

// ---------------- Kernel 1: partial rowsums, pure bf16 MFMA loop ----------------
// grid (NSTRIPE, KSPLIT) x 320 threads (5 waves x 16 i-rows).
// Wave holds its A frags in regs; per k-tile: 4 bf16x8 loads + 4 MFMA + 4 exp.
// Partial exp-rowsums plain-stored to rpart[ks][row]. No atomics, no fences.
// A/B frag: lane (r=lane&15, hi=lane>>4) holds row (..+r), channels kc*32+hi*8..+8.
// C/D frag: col k = lane&15, row i = hi*4 + j.
__global__ __launch_bounds__(320) void rowsum_kernel(const __hip_bfloat16* __restrict__ xnb,
                                                     float* __restrict__ rpart) {
    const int bi = blockIdx.x;      // stripe 0..49
    const int ks = blockIdx.y;      // k-slice 0..KSPLIT-1
    const int tid = threadIdx.x;
    const int w = tid >> 6, lane = tid & 63;
    const int r = lane & 15, hi = lane >> 4;
    const int ko = hi * 8;
    const int i0 = bi * 80 + w * 16;

    bf16x8 afrag[4];
    const __hip_bfloat16* arow = xnb + (size_t)(i0 + r) * C;
#pragma unroll
    for (int kc = 0; kc < 4; ++kc)
        afrag[kc] = *(const bf16x8*)(arow + kc * 32 + ko);

    f32x4 rsum = {0.f, 0.f, 0.f, 0.f};
#pragma unroll 2
    for (int kt = ks; kt < KTILES; kt += KSPLIT) {
        const __hip_bfloat16* brow = xnb + (size_t)(kt * 16 + r) * C;
        f32x4 acc = {0.f, 0.f, 0.f, 0.f};
#pragma unroll
        for (int kc = 0; kc < 4; ++kc) {
            bf16x8 bfrag = *(const bf16x8*)(brow + kc * 32 + ko);
            acc = __builtin_amdgcn_mfma_f32_16x16x32_bf16(afrag[kc], bfrag, acc, 0, 0, 0);
        }
#pragma unroll
        for (int j = 0; j < 4; ++j) rsum[j] += __expf(acc[j]);
    }

    // fold the 16 k-columns (lane bits 0..3), keep hi groups separate
#pragma unroll
    for (int off = 1; off < 16; off <<= 1)
#pragma unroll
        for (int j = 0; j < 4; ++j) rsum[j] += __shfl_xor(rsum[j], off);

    if (r == 0)
        *(f32x4*)(rpart + (size_t)ks * T + i0 + hi * 4) = rsum;
}

// ---------------- Kernel 2: per-5-block loss (one block per 5-block) ----------------
__global__ __launch_bounds__(64) void loss_kernel(const float* __restrict__ x,
                                                  const float* __restrict__ rpart,
                                                  const int* __restrict__ kuai2p,
                                                  float* __restrict__ out) {
    __shared__ float xs[5][C];
    __shared__ float d[5][5];
    const int b = blockIdx.x;
    const int base = b * 5;
    const int t = threadIdx.x;

    // load 5 raw fp32 rows (160 float4)
    for (int i = t; i < 160; i += 64) {
        int row = i >> 5, c4 = i & 31;
        *(float4*)&xs[row][c4 * 4] = *(const float4*)(x + (size_t)(base + row) * C + c4 * 4);
    }
    __syncthreads();

    if (t < 25) {
        int pi = t / 5, pj = t % 5;
        float s = 0.f;
#pragma unroll
        for (int c = 0; c < C; ++c) s += xs[pi][c] * xs[pj][c];
        d[pi][pj] = s;
    }
    __syncthreads();

    float contrib = 0.f;
    if (t < 20) {
        int pi = t >> 2, rr = t & 3;
        int pj = rr + (rr >= pi ? 1 : 0);
        float sii = d[pi][pi];
        float bsum = 0.f, sij = 0.f;
#pragma unroll
        for (int m = 0; m < 5; ++m) {
            float s = d[pi][m] * rsqrtf(sii * d[m][m]);   // cosine sim, fp32
            bsum += __expf(s);
            if (m == pj) sij = s;
        }
        float rs = 0.f;
#pragma unroll
        for (int k2 = 0; k2 < KSPLIT; ++k2) rs += rpart[(size_t)k2 * T + base + pi];
        float negE = CFRAC * (rs - bsum);                 // E[neg_sum]
        contrib = sij - __logf(negE + __expf(sij));       // log(pos/(neg+pos))
    }
#pragma unroll
    for (int off = 32; off; off >>= 1) contrib += __shfl_xor(contrib, off);

    if (t == 0) {
        int k = *kuai2p;
        atomicAdd(out, contrib * (-1.0f / ((float)NB * (float)k * (float)(k - 1))));
    }
}

extern "C" void kernel_launch(void* const* d_in, const int* in_sizes, int n_in,
                              void* d_out, int out_size, void* d_ws, size_t ws_size,
                              hipStream_t stream) {
    const float* x = (const float*)d_in[0];
    const int* kuai2 = (const int*)d_in[1];
    float* out = (float*)d_out;

    float* rpart = (float*)d_ws;                             // KSPLIT*T floats = 512 KB
    __hip_bfloat16* xnb = (__hip_bfloat16*)(rpart + KSPLIT * T);

    norm_kernel<<<T / 4, 256, 0, stream>>>(x, xnb, out);

    dim3 g1(NSTRIPE, KSPLIT);
    rowsum_kernel<<<g1, 320, 0, stream>>>(xnb, rpart);

    loss_kernel<<<NB, 64, 0, stream>>>(x, rpart, kuai2, out);
}

// Round 8
// 35.964 us; speedup vs baseline: 4.1811x; 1.6540x over previous
//
#include <hip/hip_runtime.h>
#include <hip/hip_bf16.h>
#include <math.h>

#define T 4000
#define C 128
#define NB 800                 // T/5
#define KTILES 250             // T/16
#define NSTRIPE 25             // T/160 stripes of 160 i-rows
#define KSPLIT 25              // k-slices; 10 k-tiles per block
#define NT 10                  // k-tiles per block
#define CFRAC (1598.0f/3995.0f)

typedef short bf16x8 __attribute__((ext_vector_type(8)));
typedef float f32x4 __attribute__((ext_vector_type(4)));

// float -> bf16 bits, round-to-nearest-even (inputs are normal finite floats)
__device__ inline unsigned short f2bf(float f) {
    union { float f; unsigned u; } v; v.f = f;
    unsigned r = v.u + 0x7fffu + ((v.u >> 16) & 1u);
    return (unsigned short)(r >> 16);
}

// ---------------- Kernel 0: normalize rows -> bf16 xnb; zero out ----------------
__global__ __launch_bounds__(256) void norm_kernel(const float* __restrict__ x,
                                                   __hip_bfloat16* __restrict__ xnb,
                                                   float* __restrict__ out) {
    if (blockIdx.x == 0 && threadIdx.x == 0) out[0] = 0.f;  // visible to K2 after boundary
    const int row = blockIdx.x * 4 + (threadIdx.x >> 6);     // grid 1000 -> 4000 rows
    const int lane = threadIdx.x & 63;
    const float* xr = x + (size_t)row * C;
    float2 v = *(const float2*)(xr + lane * 2);
    float ss = v.x * v.x + v.y * v.y;
    for (int off = 32; off; off >>= 1) ss += __shfl_xor(ss, off);
    float inv = 1.0f / fmaxf(sqrtf(ss), 1e-8f);
    unsigned o = (unsigned)f2bf(v.x * inv) | ((unsigned)f2bf(v.y * inv) << 16);
    *(unsigned*)((unsigned short*)xnb + (size_t)row * C + lane * 2) = o;
}

// ---------------- Kernel 1: partial rowsums; LDS-staged B tiles ----------------
// grid (NSTRIPE, KSPLIT) x 640 threads (10 waves x 16 i-rows = 160 rows/block).
// Block ks covers k-tiles [ks*NT, ks*NT+NT). Per tile: waves 0-3 stage their
// kc-chunk (1KB, fragment order: lane*16B) global->reg->LDS (T14 split,
// double-buffered, 1 barrier/iter); all 10 waves ds_read_b128 conflict-free,
// 4 MFMA + 4 exp. B L2-traffic: once per block per tile (10x less than r6).
// Frag layout: lane (r=lane&15, hi=lane>>4) holds row ..+r, ch kc*32+hi*8..+8.
// C/D frag: col k = lane&15, row i = hi*4 + j.
__global__ __launch_bounds__(640) void rowsum_kernel(const __hip_bfloat16* __restrict__ xnb,
                                                     float* __restrict__ rpart) {
    __shared__ __hip_bfloat16 sB[2][2048];   // 2 x 4KB tile buffers

    const int bi = blockIdx.x;      // stripe 0..24
    const int ks = blockIdx.y;      // k-slice 0..24
    const int tid = threadIdx.x;
    const int w = tid >> 6, lane = tid & 63;
    const int r = lane & 15, hi = lane >> 4;
    const int ko = hi * 8;
    const int i0 = bi * 160 + w * 16;
    const int kt0 = ks * NT;

    // A frags (held in regs for the whole sweep)
    bf16x8 afrag[4];
    const __hip_bfloat16* arow = xnb + (size_t)(i0 + r) * C;
#pragma unroll
    for (int kc = 0; kc < 4; ++kc)
        afrag[kc] = *(const bf16x8*)(arow + kc * 32 + ko);

    // prologue: stage tile 0
    if (w < 4) {
        bf16x8 s0 = *(const bf16x8*)(xnb + (size_t)(kt0 * 16 + r) * C + w * 32 + ko);
        *(bf16x8*)&sB[0][w * 512 + lane * 8] = s0;
    }
    __syncthreads();

    f32x4 rsum = {0.f, 0.f, 0.f, 0.f};
    for (int t = 0; t < NT; ++t) {
        bf16x8 stg;
        const bool doStage = (w < 4) && (t + 1 < NT);
        if (doStage)   // issue early: latency hides under compute below
            stg = *(const bf16x8*)(xnb + (size_t)((kt0 + t + 1) * 16 + r) * C + w * 32 + ko);

        f32x4 acc = {0.f, 0.f, 0.f, 0.f};
#pragma unroll
        for (int kc = 0; kc < 4; ++kc) {
            bf16x8 bfrag = *(bf16x8*)&sB[t & 1][kc * 512 + lane * 8];
            acc = __builtin_amdgcn_mfma_f32_16x16x32_bf16(afrag[kc], bfrag, acc, 0, 0, 0);
        }
#pragma unroll
        for (int j = 0; j < 4; ++j) rsum[j] += __expf(acc[j]);

        if (doStage)   // write late
            *(bf16x8*)&sB[(t + 1) & 1][w * 512 + lane * 8] = stg;
        __syncthreads();
    }

    // fold the 16 k-columns (lane bits 0..3), keep hi groups separate
#pragma unroll
    for (int off = 1; off < 16; off <<= 1)
#pragma unroll
        for (int j = 0; j < 4; ++j) rsum[j] += __shfl_xor(rsum[j], off);

    if (r == 0)
        *(f32x4*)(rpart + (size_t)ks * T + i0 + hi * 4) = rsum;
}

// ---------------- Kernel 2: per-5-block loss (one block per 5-block) ----------------
__global__ __launch_bounds__(64) void loss_kernel(const float* __restrict__ x,
                                                  const float* __restrict__ rpart,
                                                  const int* __restrict__ kuai2p,
                                                  float* __restrict__ out) {
    __shared__ float xs[5][C];
    __shared__ float d[5][5];
    __shared__ float rsp[5][5];
    const int b = blockIdx.x;
    const int base = b * 5;
    const int t = threadIdx.x;

    // cooperative rowsum gather: thread t<25 sums 5 partials for row t/5
    if (t < 25) {
        int pr = t / 5, chunk = t % 5;
        float s = 0.f;
#pragma unroll
        for (int k2 = 0; k2 < 5; ++k2)
            s += rpart[(size_t)(chunk * 5 + k2) * T + base + pr];
        rsp[pr][chunk] = s;
    }

    // load 5 raw fp32 rows (160 float4)
    for (int i = t; i < 160; i += 64) {
        int row = i >> 5, c4 = i & 31;
        *(float4*)&xs[row][c4 * 4] = *(const float4*)(x + (size_t)(base + row) * C + c4 * 4);
    }
    __syncthreads();

    if (t < 25) {
        int pi = t / 5, pj = t % 5;
        float s = 0.f;
#pragma unroll
        for (int c = 0; c < C; ++c) s += xs[pi][c] * xs[pj][c];
        d[pi][pj] = s;
    }
    __syncthreads();

    float contrib = 0.f;
    if (t < 20) {
        int pi = t >> 2, rr = t & 3;
        int pj = rr + (rr >= pi ? 1 : 0);
        float sii = d[pi][pi];
        float bsum = 0.f, sij = 0.f;
#pragma unroll
        for (int m = 0; m < 5; ++m) {
            float s = d[pi][m] * rsqrtf(sii * d[m][m]);   // cosine sim, fp32
            bsum += __expf(s);
            if (m == pj) sij = s;
        }
        float rs = rsp[pi][0] + rsp[pi][1] + rsp[pi][2] + rsp[pi][3] + rsp[pi][4];
        float negE = CFRAC * (rs - bsum);                 // E[neg_sum]
        contrib = sij - __logf(negE + __expf(sij));       // log(pos/(neg+pos))
    }
#pragma unroll
    for (int off = 32; off; off >>= 1) contrib += __shfl_xor(contrib, off);

    if (t == 0) {
        int k = *kuai2p;
        atomicAdd(out, contrib * (-1.0f / ((float)NB * (float)k * (float)(k - 1))));
    }
}

extern "C" void kernel_launch(void* const* d_in, const int* in_sizes, int n_in,
                              void* d_out, int out_size, void* d_ws, size_t ws_size,
                              hipStream_t stream) {
    const float* x = (const float*)d_in[0];
    const int* kuai2 = (const int*)d_in[1];
    float* out = (float*)d_out;

    float* rpart = (float*)d_ws;                             // KSPLIT*T floats = 400 KB
    __hip_bfloat16* xnb = (__hip_bfloat16*)(rpart + KSPLIT * T);

    norm_kernel<<<T / 4, 256, 0, stream>>>(x, xnb, out);

    dim3 g1(NSTRIPE, KSPLIT);
    rowsum_kernel<<<g1, 640, 0, stream>>>(xnb, rpart);

    loss_kernel<<<NB, 64, 0, stream>>>(x, rpart, kuai2, out);
}

// Round 9
// 35.259 us; speedup vs baseline: 4.2647x; 1.0200x over previous
//
#include <hip/hip_runtime.h>
#include <hip/hip_bf16.h>
#include <math.h>

#define T 4000
#define C 128
#define NB 800                 // T/5
#define KTILES 250             // T/16
#define NSTRIPE 25             // T/160 stripes of 160 i-rows
#define KSPLIT 25              // k-slices; NT=10 k-tiles per block
#define NT 10
#define CFRAC (1598.0f/3995.0f)

typedef short bf16x8 __attribute__((ext_vector_type(8)));
typedef float f32x4 __attribute__((ext_vector_type(4)));

// float -> bf16 bits, round-to-nearest-even (inputs are normal finite floats)
__device__ inline unsigned short f2bf(float f) {
    union { float f; unsigned u; } v; v.f = f;
    unsigned r = v.u + 0x7fffu + ((v.u >> 16) & 1u);
    return (unsigned short)(r >> 16);
}

// ---------------- Kernel 0: normalize rows -> bf16 xnb; zero out ----------------
// 250 blocks x 1024 threads (16 rows/block) — fewer blocks, faster dispatch ramp.
__global__ __launch_bounds__(1024) void norm_kernel(const float* __restrict__ x,
                                                    __hip_bfloat16* __restrict__ xnb,
                                                    float* __restrict__ out) {
    if (blockIdx.x == 0 && threadIdx.x == 0) out[0] = 0.f;  // visible to K2 after boundary
    const int row = blockIdx.x * 16 + (threadIdx.x >> 6);
    const int lane = threadIdx.x & 63;
    const float* xr = x + (size_t)row * C;
    float2 v = *(const float2*)(xr + lane * 2);
    float ss = v.x * v.x + v.y * v.y;
    for (int off = 32; off; off >>= 1) ss += __shfl_xor(ss, off);
    float inv = 1.0f / fmaxf(sqrtf(ss), 1e-8f);
    unsigned o = (unsigned)f2bf(v.x * inv) | ((unsigned)f2bf(v.y * inv) << 16);
    *(unsigned*)((unsigned short*)xnb + (size_t)row * C + lane * 2) = o;
}

// ---------------- Kernel 1: partial rowsums; LDS-staged B, 2 tiles/barrier ----------------
// grid (NSTRIPE, KSPLIT) x 640 threads (10 waves x 16 i-rows = 160 rows/block).
// 4 LDS tile buffers; per barrier period: waves 0-3 issue loads for tiles 2t+2,2t+3
// (early), all waves compute tiles 2t,2t+1 (8 MFMA + 8 exp), staging waves write
// late, one barrier. Issue->write distance ~2 compute phases hides L2 latency.
// Frag layout: lane (r=lane&15, hi=lane>>4) holds row ..+r, ch kc*32+hi*8..+8.
// C/D frag: col k = lane&15, row i = hi*4 + j.
__global__ __launch_bounds__(640) void rowsum_kernel(const __hip_bfloat16* __restrict__ xnb,
                                                     float* __restrict__ rpart) {
    __shared__ __hip_bfloat16 sB[4][2048];   // 4 x 4KB tile buffers

    const int bi = blockIdx.x;      // stripe 0..24
    const int ks = blockIdx.y;      // k-slice 0..24
    const int tid = threadIdx.x;
    const int w = tid >> 6, lane = tid & 63;
    const int r = lane & 15, hi = lane >> 4;
    const int ko = hi * 8;
    const int i0 = bi * 160 + w * 16;
    const int kt0 = ks * NT;

    // A frags (held in regs for the whole sweep)
    bf16x8 afrag[4];
    const __hip_bfloat16* arow = xnb + (size_t)(i0 + r) * C;
#pragma unroll
    for (int kc = 0; kc < 4; ++kc)
        afrag[kc] = *(const bf16x8*)(arow + kc * 32 + ko);

    // staging lane's per-tile source base (valid for w<4): row kt*16+r, ch w*32+ko
    const __hip_bfloat16* bsrc = xnb + (size_t)r * C + w * 32 + ko;

    // prologue: stage tiles 0,1
    if (w < 4) {
        bf16x8 s0 = *(const bf16x8*)(bsrc + (size_t)(kt0 + 0) * 16 * C);
        bf16x8 s1 = *(const bf16x8*)(bsrc + (size_t)(kt0 + 1) * 16 * C);
        *(bf16x8*)&sB[0][w * 512 + lane * 8] = s0;
        *(bf16x8*)&sB[1][w * 512 + lane * 8] = s1;
    }
    __syncthreads();

    f32x4 rsum = {0.f, 0.f, 0.f, 0.f};
    for (int tp = 0; tp < NT / 2; ++tp) {
        bf16x8 stg0, stg1;
        const bool doStage = (w < 4) && (tp + 1 < NT / 2);
        if (doStage) {   // issue early: 2 tiles in flight across the whole compute phase
            stg0 = *(const bf16x8*)(bsrc + (size_t)(kt0 + 2 * tp + 2) * 16 * C);
            stg1 = *(const bf16x8*)(bsrc + (size_t)(kt0 + 2 * tp + 3) * 16 * C);
        }

        f32x4 acc0 = {0.f, 0.f, 0.f, 0.f}, acc1 = {0.f, 0.f, 0.f, 0.f};
#pragma unroll
        for (int kc = 0; kc < 4; ++kc) {
            bf16x8 b0 = *(bf16x8*)&sB[(2 * tp) & 3][kc * 512 + lane * 8];
            acc0 = __builtin_amdgcn_mfma_f32_16x16x32_bf16(afrag[kc], b0, acc0, 0, 0, 0);
        }
#pragma unroll
        for (int kc = 0; kc < 4; ++kc) {
            bf16x8 b1 = *(bf16x8*)&sB[(2 * tp + 1) & 3][kc * 512 + lane * 8];
            acc1 = __builtin_amdgcn_mfma_f32_16x16x32_bf16(afrag[kc], b1, acc1, 0, 0, 0);
        }
#pragma unroll
        for (int j = 0; j < 4; ++j) rsum[j] += __expf(acc0[j]) + __expf(acc1[j]);

        if (doStage) {   // write late; target buffers not in use this period
            *(bf16x8*)&sB[(2 * tp + 2) & 3][w * 512 + lane * 8] = stg0;
            *(bf16x8*)&sB[(2 * tp + 3) & 3][w * 512 + lane * 8] = stg1;
        }
        __syncthreads();
    }

    // fold the 16 k-columns (lane bits 0..3), keep hi groups separate
#pragma unroll
    for (int off = 1; off < 16; off <<= 1)
#pragma unroll
        for (int j = 0; j < 4; ++j) rsum[j] += __shfl_xor(rsum[j], off);

    if (r == 0)
        *(f32x4*)(rpart + (size_t)ks * T + i0 + hi * 4) = rsum;
}

// ---------------- Kernel 2: per-5-block loss (one block per 5-block) ----------------
__global__ __launch_bounds__(64) void loss_kernel(const float* __restrict__ x,
                                                  const float* __restrict__ rpart,
                                                  const int* __restrict__ kuai2p,
                                                  float* __restrict__ out) {
    __shared__ float xs[5][C];
    __shared__ float d[5][5];
    __shared__ float rsp[5][5];
    const int b = blockIdx.x;
    const int base = b * 5;
    const int t = threadIdx.x;

    // cooperative rowsum gather: thread t<25 sums 5 partials for row t/5
    if (t < 25) {
        int pr = t / 5, chunk = t % 5;
        float s = 0.f;
#pragma unroll
        for (int k2 = 0; k2 < 5; ++k2)
            s += rpart[(size_t)(chunk * 5 + k2) * T + base + pr];
        rsp[pr][chunk] = s;
    }

    // load 5 raw fp32 rows (160 float4)
    for (int i = t; i < 160; i += 64) {
        int row = i >> 5, c4 = i & 31;
        *(float4*)&xs[row][c4 * 4] = *(const float4*)(x + (size_t)(base + row) * C + c4 * 4);
    }
    __syncthreads();

    if (t < 25) {
        int pi = t / 5, pj = t % 5;
        float s = 0.f;
#pragma unroll
        for (int c = 0; c < C; ++c) s += xs[pi][c] * xs[pj][c];
        d[pi][pj] = s;
    }
    __syncthreads();

    float contrib = 0.f;
    if (t < 20) {
        int pi = t >> 2, rr = t & 3;
        int pj = rr + (rr >= pi ? 1 : 0);
        float sii = d[pi][pi];
        float bsum = 0.f, sij = 0.f;
#pragma unroll
        for (int m = 0; m < 5; ++m) {
            float s = d[pi][m] * rsqrtf(sii * d[m][m]);   // cosine sim, fp32
            bsum += __expf(s);
            if (m == pj) sij = s;
        }
        float rs = rsp[pi][0] + rsp[pi][1] + rsp[pi][2] + rsp[pi][3] + rsp[pi][4];
        float negE = CFRAC * (rs - bsum);                 // E[neg_sum]
        contrib = sij - __logf(negE + __expf(sij));       // log(pos/(neg+pos))
    }
#pragma unroll
    for (int off = 32; off; off >>= 1) contrib += __shfl_xor(contrib, off);

    if (t == 0) {
        int k = *kuai2p;
        atomicAdd(out, contrib * (-1.0f / ((float)NB * (float)k * (float)(k - 1))));
    }
}

extern "C" void kernel_launch(void* const* d_in, const int* in_sizes, int n_in,
                              void* d_out, int out_size, void* d_ws, size_t ws_size,
                              hipStream_t stream) {
    const float* x = (const float*)d_in[0];
    const int* kuai2 = (const int*)d_in[1];
    float* out = (float*)d_out;

    float* rpart = (float*)d_ws;                             // KSPLIT*T floats = 400 KB
    __hip_bfloat16* xnb = (__hip_bfloat16*)(rpart + KSPLIT * T);

    norm_kernel<<<T / 16, 1024, 0, stream>>>(x, xnb, out);

    dim3 g1(NSTRIPE, KSPLIT);
    rowsum_kernel<<<g1, 640, 0, stream>>>(xnb, rpart);

    loss_kernel<<<NB, 64, 0, stream>>>(x, rpart, kuai2, out);
}